// Round 8
// baseline (108.169 us; speedup 1.0000x reference)
//
#include <hip/hip_runtime.h>

#define EMB 256
#define HD 32
#define SEQ 4096
#define NSPLIT 16     // key splits across blocks
#define KRANGE 256    // keys per block (shared by its 4 waves)
#define NQROW 16384   // B*S

typedef _Float16 half8 __attribute__((ext_vector_type(8)));
typedef _Float16 half4v __attribute__((ext_vector_type(4)));
typedef float floatx4 __attribute__((ext_vector_type(4)));
typedef float floatx16 __attribute__((ext_vector_type(16)));

#define L2E 1.44269504088896340736f
#define SCALING 0.17677669529663687f   // 32^-0.5, applied POST-softmax

__device__ __forceinline__ half8 mk8(unsigned a, unsigned b, unsigned c, unsigned d) {
  union { unsigned u[4]; half8 h; } z;
  z.u[0] = a; z.u[1] = b; z.u[2] = c; z.u[3] = d;
  return z.h;
}

// ---------------- Kernel 0: swizzle W into MFMA B-frag order (f16), Wq pre-scaled by L2E ----------------
__global__ __launch_bounds__(256) void prep_kernel(const float* __restrict__ Wq,
                                                   const float* __restrict__ Wk,
                                                   const float* __restrict__ Wv,
                                                   _Float16* __restrict__ wsw) {
  int gid = blockIdx.x * 256 + threadIdx.x;   // [0, 24576)
  int j    = gid & 7;
  int lane = (gid >> 3) & 63;
  int kc   = (gid >> 9) & 7;
  int half = (gid >> 12) & 1;
  int mat  = gid >> 13;
  const float* W = (mat == 0) ? Wq : ((mat == 1) ? Wk : Wv);
  int n = lane & 15, quad = lane >> 4;
  int e = kc * 32 + quad * 8 + j;
  int d = n + half * 16;
  float v = W[e * HD + d];
  if (mat == 0) v *= L2E;                     // exp2-domain scores for free
  wsw[gid] = (_Float16)v;
}

// ---------------- Kernel 1: QKV projection, split by matrix (grid 256 x 3) ----------------
__global__ __launch_bounds__(256) void qkv_kernel(const float* __restrict__ x,
                                                  const _Float16* __restrict__ wsw,
                                                  _Float16* __restrict__ qw,
                                                  _Float16* __restrict__ kw,
                                                  _Float16* __restrict__ vt) {
  int lane = threadIdx.x & 63, wave = threadIdx.x >> 6;
  int n = lane & 15, quad = lane >> 4;
  int mat = blockIdx.y;
  int rowbase = blockIdx.x * 64 + wave * 16;

  floatx4 c0 = {0,0,0,0}, c1 = {0,0,0,0};

#pragma unroll
  for (int kc = 0; kc < 8; ++kc) {
    const float* xp = x + (rowbase + n) * EMB + kc * 32 + quad * 8;
    float4 xa = *(const float4*)(xp);
    float4 xb = *(const float4*)(xp + 4);
    half8 a;
    a[0] = (_Float16)xa.x; a[1] = (_Float16)xa.y; a[2] = (_Float16)xa.z; a[3] = (_Float16)xa.w;
    a[4] = (_Float16)xb.x; a[5] = (_Float16)xb.y; a[6] = (_Float16)xb.z; a[7] = (_Float16)xb.w;
    half8 b0 = *(const half8*)(wsw + (((mat * 2 + 0) * 8 + kc) << 9) + (lane << 3));
    half8 b1 = *(const half8*)(wsw + (((mat * 2 + 1) * 8 + kc) << 9) + (lane << 3));
    c0 = __builtin_amdgcn_mfma_f32_16x16x32_f16(a, b0, c0, 0, 0, 0);
    c1 = __builtin_amdgcn_mfma_f32_16x16x32_f16(a, b1, c1, 0, 0, 0);
  }

  if (mat == 2) {
    int b = rowbase >> 12;
    int s0 = rowbase & (SEQ - 1);
    _Float16* vb = vt + b * HD * SEQ;
#pragma unroll
    for (int r = 0; r < 4; ++r) {
      int s = s0 + quad * 4 + r;
      vb[n * SEQ + s]        = (_Float16)c0[r];
      vb[(n + 16) * SEQ + s] = (_Float16)c1[r];
    }
  } else {
    _Float16* dst = (mat == 0) ? qw : kw;
#pragma unroll
    for (int r = 0; r < 4; ++r) {
      int row = rowbase + quad * 4 + r;
      dst[row * HD + n]      = (_Float16)c0[r];
      dst[row * HD + n + 16] = (_Float16)c1[r];
    }
  }
}

// ---------------- Kernel 2: flash attention on 32x32x16 MFMA, O^T orientation ----------------
// 2048 blocks x 256 thr (4 waves) = 8 blocks/CU x 4 waves = 32 waves/CU (max occupancy).
// Wave owns 32 q-rows; block's 4 waves share keys [sp*256, +256) in 8 tiles of 32.
// Explicit 2-deep pipeline: tile kt+1's A-frags are in flight during tile kt's softmax.
__global__ __launch_bounds__(256, 4) void attn_kernel(const _Float16* __restrict__ q,
                                                      const _Float16* __restrict__ k,
                                                      const _Float16* __restrict__ vt,
                                                      _Float16* __restrict__ Op,
                                                      float* __restrict__ Mp,
                                                      float* __restrict__ Lp) {
  const int t = threadIdx.x;
  const int w = t >> 6, lane = t & 63;
  const int n2 = lane & 31, h = lane >> 5;
  const int qb = blockIdx.x & 127;
  const int sp = blockIdx.x >> 7;
  const int b = qb >> 5;
  const int qrow0 = qb * 128 + w * 32;
  const int key0 = sp * KRANGE;

  const _Float16* kb = k  + (size_t)(b * SEQ + key0) * HD;
  const _Float16* vb = vt + (size_t)b * HD * SEQ + key0;

  // Q^T B-frags (pre-scaled by L2E): B[k=d][n=qrow=n2]
  half8 qb0 = *(const half8*)(q + (qrow0 + n2) * HD + h * 8);
  half8 qb1 = *(const half8*)(q + (qrow0 + n2) * HD + 16 + h * 8);

  floatx16 o;
#pragma unroll
  for (int r = 0; r < 16; ++r) o[r] = 0.f;
  const floatx16 zero16 = o;
  float m = -__builtin_huge_valf();
  float l = 0.f;

  // prefetch tile 0
  const _Float16* kp = kb + (size_t)n2 * HD;
  const _Float16* vp = vb + (size_t)n2 * SEQ;
  half8 ka0 = *(const half8*)(kp + h * 8);
  half8 ka1 = *(const half8*)(kp + 16 + h * 8);
  half8 va0 = *(const half8*)(vp + h * 8);
  half8 va1 = *(const half8*)(vp + 16 + h * 8);

#pragma unroll
  for (int kt = 0; kt < KRANGE / 32; ++kt) {
    // issue tile kt+1 loads first (in flight through the softmax below)
    half8 nka0, nka1, nva0, nva1;
    if (kt + 1 < KRANGE / 32) {
      const _Float16* kn = kb + (size_t)((kt + 1) * 32 + n2) * HD;
      const _Float16* vn = vb + (size_t)n2 * SEQ + (kt + 1) * 32;
      nka0 = *(const half8*)(kn + h * 8);
      nka1 = *(const half8*)(kn + 16 + h * 8);
      nva0 = *(const half8*)(vn + h * 8);
      nva1 = *(const half8*)(vn + 16 + h * 8);
    }

    // S^T tile [32 keys x 32 qrows], accumulate over the two d-halves
    floatx16 s = __builtin_amdgcn_mfma_f32_32x32x16_f16(ka0, qb0, zero16, 0, 0, 0);
    s = __builtin_amdgcn_mfma_f32_32x32x16_f16(ka1, qb1, s, 0, 0, 0);

    // per-lane max over 16 scores (all of q-row n2), then merge the lane^32 partner
    floatx4 s0 = {s[0], s[1], s[2], s[3]};
    floatx4 s1 = {s[4], s[5], s[6], s[7]};
    floatx4 s2 = {s[8], s[9], s[10], s[11]};
    floatx4 s3 = {s[12], s[13], s[14], s[15]};
    floatx4 t01 = __builtin_elementwise_max(s0, s1);
    floatx4 t23 = __builtin_elementwise_max(s2, s3);
    floatx4 t4  = __builtin_elementwise_max(t01, t23);
    float mm = fmaxf(fmaxf(t4[0], t4[1]), fmaxf(t4[2], t4[3]));
    mm = fmaxf(mm, __shfl_xor(mm, 32));
    float mnew = fmaxf(m, mm);
    float alpha = __builtin_amdgcn_exp2f(m - mnew);
    m = mnew;

    // p = exp2(s - m), pack consecutive-key pairs
    float p[16];
#pragma unroll
    for (int r = 0; r < 16; ++r) p[r] = __builtin_amdgcn_exp2f(s[r] - mnew);
    unsigned pk[8];
#pragma unroll
    for (int g = 0; g < 8; ++g)
      pk[g] = __builtin_bit_cast(unsigned, __builtin_amdgcn_cvt_pkrtz(p[2 * g], p[2 * g + 1]));

    // l update: own 16 + partner 16
    float ps = ((p[0] + p[1]) + (p[2] + p[3])) + ((p[4] + p[5]) + (p[6] + p[7]))
             + ((p[8] + p[9]) + (p[10] + p[11])) + ((p[12] + p[13]) + (p[14] + p[15]));
    ps += __shfl_xor(ps, 32);
    l = l * alpha + ps;

#pragma unroll
    for (int r = 0; r < 16; ++r) o[r] *= alpha;

    // P^T B-frags: key of reg r = (r&3) + 8*(r>>2) + 4h -> exchange across lane^32
    unsigned tmp0 = h ? pk[0] : pk[2];
    unsigned tmp1 = h ? pk[1] : pk[3];
    unsigned tmp2 = h ? pk[4] : pk[6];
    unsigned tmp3 = h ? pk[5] : pk[7];
    unsigned ex0 = (unsigned)__shfl_xor((int)tmp0, 32);
    unsigned ex1 = (unsigned)__shfl_xor((int)tmp1, 32);
    unsigned ex2 = (unsigned)__shfl_xor((int)tmp2, 32);
    unsigned ex3 = (unsigned)__shfl_xor((int)tmp3, 32);
    half8 B0 = h ? mk8(ex0, ex1, pk[2], pk[3]) : mk8(pk[0], pk[1], ex0, ex1);
    half8 B1 = h ? mk8(ex2, ex3, pk[6], pk[7]) : mk8(pk[4], pk[5], ex2, ex3);

    // O^T += V^T · P^T  (two key halves)
    o = __builtin_amdgcn_mfma_f32_32x32x16_f16(va0, B0, o, 0, 0, 0);
    o = __builtin_amdgcn_mfma_f32_32x32x16_f16(va1, B1, o, 0, 0, 0);

    ka0 = nka0; ka1 = nka1; va0 = nva0; va1 = nva1;
  }

  // epilogue: lane(n2,h) reg r -> qrow=n2, d=(r&3)+8*(r>>2)+4h; half4 stores
  size_t obase = ((size_t)(sp * NQROW + qrow0) + n2) * 32;
#pragma unroll
  for (int bb = 0; bb < 4; ++bb) {
    half4v pv;
    pv[0] = (_Float16)o[4 * bb + 0];
    pv[1] = (_Float16)o[4 * bb + 1];
    pv[2] = (_Float16)o[4 * bb + 2];
    pv[3] = (_Float16)o[4 * bb + 3];
    *(half4v*)&Op[obase + 8 * bb + 4 * h] = pv;
  }
  if (h == 0) {
    int mi = sp * NQROW + qrow0 + n2;
    Mp[mi] = m;
    Lp[mi] = l;
  }
}

// ---------------- Kernel 3: merge the 16 key-splits, normalize, scale ----------------
__global__ __launch_bounds__(256) void combine_kernel(const _Float16* __restrict__ Op,
                                                      const float* __restrict__ Mp,
                                                      const float* __restrict__ Lp,
                                                      float* __restrict__ out) {
  int gid = blockIdx.x * 256 + threadIdx.x;   // [0, 131072)
  int dc = gid & 7, qrow = gid >> 3;
  float mv[NSPLIT];
  float ms = -__builtin_huge_valf();
#pragma unroll
  for (int sp = 0; sp < NSPLIT; ++sp) {
    mv[sp] = Mp[sp * NQROW + qrow];
    ms = fmaxf(ms, mv[sp]);
  }
  float L = 0.f;
  floatx4 O = {0.f, 0.f, 0.f, 0.f};
#pragma unroll
  for (int sp = 0; sp < NSPLIT; ++sp) {
    float ww = __builtin_amdgcn_exp2f(mv[sp] - ms);
    L += ww * Lp[sp * NQROW + qrow];
    half4v ov = *(const half4v*)&Op[((size_t)(sp * NQROW + qrow)) * 32 + dc * 4];
#pragma unroll
    for (int r = 0; r < 4; ++r) O[r] += ww * (float)ov[r];
  }
  float inv = SCALING / L;
  floatx4 res = {O[0] * inv, O[1] * inv, O[2] * inv, O[3] * inv};
  *(floatx4*)&out[qrow * HD + dc * 4] = res;
}

extern "C" void kernel_launch(void* const* d_in, const int* in_sizes, int n_in,
                              void* d_out, int out_size, void* d_ws, size_t ws_size,
                              hipStream_t stream) {
  const float* x  = (const float*)d_in[0];
  const float* Wq = (const float*)d_in[1];
  const float* Wk = (const float*)d_in[2];
  const float* Wv = (const float*)d_in[3];
  float* out = (float*)d_out;

  _Float16* wsw = (_Float16*)d_ws;          // 24576 f16
  _Float16* qw  = wsw + 24576;              // [16384][32]
  _Float16* kw  = qw + NQROW * HD;          // [16384][32]
  _Float16* vt  = kw + NQROW * HD;          // [4][32][4096]
  _Float16* Op  = vt + NQROW * HD;          // [16][16384][32] f16 (16 MB)
  float* Mp = (float*)(Op + (size_t)NSPLIT * NQROW * 32);  // [16][16384]
  float* Lp = Mp + NSPLIT * NQROW;                         // [16][16384]

  prep_kernel<<<96, 256, 0, stream>>>(Wq, Wk, Wv, wsw);
  qkv_kernel<<<dim3(256, 3), 256, 0, stream>>>(x, wsw, qw, kw, vt);
  attn_kernel<<<2048, 256, 0, stream>>>(qw, kw, vt, Op, Mp, Lp);
  combine_kernel<<<512, 256, 0, stream>>>(Op, Mp, Lp, out);
}

// Round 9
// 99.588 us; speedup vs baseline: 1.0862x; 1.0862x over previous
//
#include <hip/hip_runtime.h>

#define EMB 256
#define HD 32
#define SEQ 4096
#define NSPLIT 16     // key splits across blocks
#define KRANGE 256    // keys per block (shared by its 4 waves)
#define NQROW 16384   // B*S

typedef _Float16 half8 __attribute__((ext_vector_type(8)));
typedef _Float16 half4v __attribute__((ext_vector_type(4)));
typedef float floatx4 __attribute__((ext_vector_type(4)));
typedef float floatx16 __attribute__((ext_vector_type(16)));

#define L2E 1.44269504088896340736f
#define SCALING 0.17677669529663687f   // 32^-0.5, applied POST-softmax

__device__ __forceinline__ half8 mk8(unsigned a, unsigned b, unsigned c, unsigned d) {
  union { unsigned u[4]; half8 h; } z;
  z.u[0] = a; z.u[1] = b; z.u[2] = c; z.u[3] = d;
  return z.h;
}

// ---------------- Kernel 0: swizzle W into MFMA B-frag order (f16), Wq pre-scaled by L2E ----------------
__global__ __launch_bounds__(256) void prep_kernel(const float* __restrict__ Wq,
                                                   const float* __restrict__ Wk,
                                                   const float* __restrict__ Wv,
                                                   _Float16* __restrict__ wsw) {
  int gid = blockIdx.x * 256 + threadIdx.x;   // [0, 24576)
  int j    = gid & 7;
  int lane = (gid >> 3) & 63;
  int kc   = (gid >> 9) & 7;
  int half = (gid >> 12) & 1;
  int mat  = gid >> 13;
  const float* W = (mat == 0) ? Wq : ((mat == 1) ? Wk : Wv);
  int n = lane & 15, quad = lane >> 4;
  int e = kc * 32 + quad * 8 + j;
  int d = n + half * 16;
  float v = W[e * HD + d];
  if (mat == 0) v *= L2E;                     // exp2-domain scores for free
  wsw[gid] = (_Float16)v;
}

// ---------------- Kernel 1: QKV projection, split by matrix (grid 256 x 3) ----------------
// V stored key-tiled: vt2[b][s>>3][d][s&7] so attn's PV A-frag loads are lane-contiguous.
__global__ __launch_bounds__(256) void qkv_kernel(const float* __restrict__ x,
                                                  const _Float16* __restrict__ wsw,
                                                  _Float16* __restrict__ qw,
                                                  _Float16* __restrict__ kw,
                                                  _Float16* __restrict__ vt2) {
  int lane = threadIdx.x & 63, wave = threadIdx.x >> 6;
  int n = lane & 15, quad = lane >> 4;
  int mat = blockIdx.y;
  int rowbase = blockIdx.x * 64 + wave * 16;

  floatx4 c0 = {0,0,0,0}, c1 = {0,0,0,0};

#pragma unroll
  for (int kc = 0; kc < 8; ++kc) {
    const float* xp = x + (rowbase + n) * EMB + kc * 32 + quad * 8;
    float4 xa = *(const float4*)(xp);
    float4 xb = *(const float4*)(xp + 4);
    half8 a;
    a[0] = (_Float16)xa.x; a[1] = (_Float16)xa.y; a[2] = (_Float16)xa.z; a[3] = (_Float16)xa.w;
    a[4] = (_Float16)xb.x; a[5] = (_Float16)xb.y; a[6] = (_Float16)xb.z; a[7] = (_Float16)xb.w;
    half8 b0 = *(const half8*)(wsw + (((mat * 2 + 0) * 8 + kc) << 9) + (lane << 3));
    half8 b1 = *(const half8*)(wsw + (((mat * 2 + 1) * 8 + kc) << 9) + (lane << 3));
    c0 = __builtin_amdgcn_mfma_f32_16x16x32_f16(a, b0, c0, 0, 0, 0);
    c1 = __builtin_amdgcn_mfma_f32_16x16x32_f16(a, b1, c1, 0, 0, 0);
  }

  if (mat == 2) {
    int b = rowbase >> 12;
    int s0 = rowbase & (SEQ - 1);
    _Float16* vb = vt2 + (size_t)b * SEQ * HD;
#pragma unroll
    for (int r = 0; r < 4; ++r) {
      int s = s0 + quad * 4 + r;
      int blk = (s >> 3) << 8, sl = s & 7;   // key-block base (8 keys x 32 d), slot
      vb[blk + n * 8 + sl]        = (_Float16)c0[r];
      vb[blk + (n + 16) * 8 + sl] = (_Float16)c1[r];
    }
  } else {
    _Float16* dst = (mat == 0) ? qw : kw;
#pragma unroll
    for (int r = 0; r < 4; ++r) {
      int row = rowbase + quad * 4 + r;
      dst[row * HD + n]      = (_Float16)c0[r];
      dst[row * HD + n + 16] = (_Float16)c1[r];
    }
  }
}

// ---------------- Kernel 2: flash attention on 32x32x16 MFMA, O^T orientation ----------------
// 2048 blocks x 256 thr (4 waves) = 32 waves/CU. Wave owns 32 q-rows; block's 4 waves share
// keys [sp*256, +256) in 8 tiles of 32. All four frag loads (K and V) are now 1KB-contiguous
// per instruction. 2-deep prefetch pipeline.
__global__ __launch_bounds__(256, 4) void attn_kernel(const _Float16* __restrict__ q,
                                                      const _Float16* __restrict__ k,
                                                      const _Float16* __restrict__ vt2,
                                                      _Float16* __restrict__ Op,
                                                      float* __restrict__ Mp,
                                                      float* __restrict__ Lp) {
  const int t = threadIdx.x;
  const int w = t >> 6, lane = t & 63;
  const int n2 = lane & 31, h = lane >> 5;
  const int qb = blockIdx.x & 127;
  const int sp = blockIdx.x >> 7;
  const int b = qb >> 5;
  const int qrow0 = qb * 128 + w * 32;
  const int key0 = sp * KRANGE;

  const _Float16* kb = k   + (size_t)(b * SEQ + key0) * HD;
  const _Float16* vb = vt2 + (size_t)b * SEQ * HD + (size_t)key0 * HD;  // key*32 elems

  // Q^T B-frags (pre-scaled by L2E): B[k=d][n=qrow=n2]
  half8 qb0 = *(const half8*)(q + (qrow0 + n2) * HD + h * 8);
  half8 qb1 = *(const half8*)(q + (qrow0 + n2) * HD + 16 + h * 8);

  floatx16 o;
#pragma unroll
  for (int r = 0; r < 16; ++r) o[r] = 0.f;
  const floatx16 zero16 = o;
  float m = -__builtin_huge_valf();
  float l = 0.f;

  // prefetch tile 0. V^T A-frag: A[m=d=n2][k=key=8h+j] -> vtile + h*256 + n2*8 (+512)
  half8 ka0 = *(const half8*)(kb + (size_t)n2 * HD + h * 8);
  half8 ka1 = *(const half8*)(kb + (size_t)n2 * HD + 16 + h * 8);
  half8 va0 = *(const half8*)(vb + h * 256 + n2 * 8);
  half8 va1 = *(const half8*)(vb + 512 + h * 256 + n2 * 8);

#pragma unroll
  for (int kt = 0; kt < KRANGE / 32; ++kt) {
    // issue tile kt+1 loads first (in flight through the softmax below)
    half8 nka0, nka1, nva0, nva1;
    if (kt + 1 < KRANGE / 32) {
      const _Float16* kn = kb + (size_t)((kt + 1) * 32 + n2) * HD;
      const _Float16* vn = vb + (kt + 1) * 1024;
      nka0 = *(const half8*)(kn + h * 8);
      nka1 = *(const half8*)(kn + 16 + h * 8);
      nva0 = *(const half8*)(vn + h * 256 + n2 * 8);
      nva1 = *(const half8*)(vn + 512 + h * 256 + n2 * 8);
    }

    // S^T tile [32 keys x 32 qrows], accumulate over the two d-halves
    floatx16 s = __builtin_amdgcn_mfma_f32_32x32x16_f16(ka0, qb0, zero16, 0, 0, 0);
    s = __builtin_amdgcn_mfma_f32_32x32x16_f16(ka1, qb1, s, 0, 0, 0);

    // per-lane max over 16 scores (all of q-row n2), then merge the lane^32 partner
    floatx4 s0 = {s[0], s[1], s[2], s[3]};
    floatx4 s1 = {s[4], s[5], s[6], s[7]};
    floatx4 s2 = {s[8], s[9], s[10], s[11]};
    floatx4 s3 = {s[12], s[13], s[14], s[15]};
    floatx4 t01 = __builtin_elementwise_max(s0, s1);
    floatx4 t23 = __builtin_elementwise_max(s2, s3);
    floatx4 t4  = __builtin_elementwise_max(t01, t23);
    float mm = fmaxf(fmaxf(t4[0], t4[1]), fmaxf(t4[2], t4[3]));
    mm = fmaxf(mm, __shfl_xor(mm, 32));
    float mnew = fmaxf(m, mm);
    float alpha = __builtin_amdgcn_exp2f(m - mnew);
    m = mnew;

    // p = exp2(s - m), pack consecutive-key pairs
    float p[16];
#pragma unroll
    for (int r = 0; r < 16; ++r) p[r] = __builtin_amdgcn_exp2f(s[r] - mnew);
    unsigned pk[8];
#pragma unroll
    for (int g = 0; g < 8; ++g)
      pk[g] = __builtin_bit_cast(unsigned, __builtin_amdgcn_cvt_pkrtz(p[2 * g], p[2 * g + 1]));

    // l update: own 16 + partner 16
    float ps = ((p[0] + p[1]) + (p[2] + p[3])) + ((p[4] + p[5]) + (p[6] + p[7]))
             + ((p[8] + p[9]) + (p[10] + p[11])) + ((p[12] + p[13]) + (p[14] + p[15]));
    ps += __shfl_xor(ps, 32);
    l = l * alpha + ps;

#pragma unroll
    for (int r = 0; r < 16; ++r) o[r] *= alpha;

    // P^T B-frags: key of reg r = (r&3) + 8*(r>>2) + 4h -> exchange across lane^32
    unsigned tmp0 = h ? pk[0] : pk[2];
    unsigned tmp1 = h ? pk[1] : pk[3];
    unsigned tmp2 = h ? pk[4] : pk[6];
    unsigned tmp3 = h ? pk[5] : pk[7];
    unsigned ex0 = (unsigned)__shfl_xor((int)tmp0, 32);
    unsigned ex1 = (unsigned)__shfl_xor((int)tmp1, 32);
    unsigned ex2 = (unsigned)__shfl_xor((int)tmp2, 32);
    unsigned ex3 = (unsigned)__shfl_xor((int)tmp3, 32);
    half8 B0 = h ? mk8(ex0, ex1, pk[2], pk[3]) : mk8(pk[0], pk[1], ex0, ex1);
    half8 B1 = h ? mk8(ex2, ex3, pk[6], pk[7]) : mk8(pk[4], pk[5], ex2, ex3);

    // O^T += V^T · P^T  (two key halves)
    o = __builtin_amdgcn_mfma_f32_32x32x16_f16(va0, B0, o, 0, 0, 0);
    o = __builtin_amdgcn_mfma_f32_32x32x16_f16(va1, B1, o, 0, 0, 0);

    ka0 = nka0; ka1 = nka1; va0 = nva0; va1 = nva1;
  }

  // epilogue: lane(n2,h) reg r -> qrow=n2, d=(r&3)+8*(r>>2)+4h; half4 stores
  size_t obase = ((size_t)(sp * NQROW + qrow0) + n2) * 32;
#pragma unroll
  for (int bb = 0; bb < 4; ++bb) {
    half4v pv;
    pv[0] = (_Float16)o[4 * bb + 0];
    pv[1] = (_Float16)o[4 * bb + 1];
    pv[2] = (_Float16)o[4 * bb + 2];
    pv[3] = (_Float16)o[4 * bb + 3];
    *(half4v*)&Op[obase + 8 * bb + 4 * h] = pv;
  }
  if (h == 0) {
    int mi = sp * NQROW + qrow0 + n2;
    Mp[mi] = m;
    Lp[mi] = l;
  }
}

// ---------------- Kernel 3: merge the 16 key-splits, normalize, scale ----------------
__global__ __launch_bounds__(256) void combine_kernel(const _Float16* __restrict__ Op,
                                                      const float* __restrict__ Mp,
                                                      const float* __restrict__ Lp,
                                                      float* __restrict__ out) {
  int gid = blockIdx.x * 256 + threadIdx.x;   // [0, 131072)
  int dc = gid & 7, qrow = gid >> 3;
  float mv[NSPLIT];
  float ms = -__builtin_huge_valf();
#pragma unroll
  for (int sp = 0; sp < NSPLIT; ++sp) {
    mv[sp] = Mp[sp * NQROW + qrow];
    ms = fmaxf(ms, mv[sp]);
  }
  float L = 0.f;
  floatx4 O = {0.f, 0.f, 0.f, 0.f};
#pragma unroll
  for (int sp = 0; sp < NSPLIT; ++sp) {
    float ww = __builtin_amdgcn_exp2f(mv[sp] - ms);
    L += ww * Lp[sp * NQROW + qrow];
    half4v ov = *(const half4v*)&Op[((size_t)(sp * NQROW + qrow)) * 32 + dc * 4];
#pragma unroll
    for (int r = 0; r < 4; ++r) O[r] += ww * (float)ov[r];
  }
  float inv = SCALING / L;
  floatx4 res = {O[0] * inv, O[1] * inv, O[2] * inv, O[3] * inv};
  *(floatx4*)&out[qrow * HD + dc * 4] = res;
}

extern "C" void kernel_launch(void* const* d_in, const int* in_sizes, int n_in,
                              void* d_out, int out_size, void* d_ws, size_t ws_size,
                              hipStream_t stream) {
  const float* x  = (const float*)d_in[0];
  const float* Wq = (const float*)d_in[1];
  const float* Wk = (const float*)d_in[2];
  const float* Wv = (const float*)d_in[3];
  float* out = (float*)d_out;

  _Float16* wsw = (_Float16*)d_ws;          // 24576 f16
  _Float16* qw  = wsw + 24576;              // [16384][32]
  _Float16* kw  = qw + NQROW * HD;          // [16384][32]
  _Float16* vt2 = kw + NQROW * HD;          // [4][512][32][8] key-tiled V
  _Float16* Op  = vt2 + NQROW * HD;         // [16][16384][32] f16 (16 MB)
  float* Mp = (float*)(Op + (size_t)NSPLIT * NQROW * 32);  // [16][16384]
  float* Lp = Mp + NSPLIT * NQROW;                         // [16][16384]

  prep_kernel<<<96, 256, 0, stream>>>(Wq, Wk, Wv, wsw);
  qkv_kernel<<<dim3(256, 3), 256, 0, stream>>>(x, wsw, qw, kw, vt2);
  attn_kernel<<<2048, 256, 0, stream>>>(qw, kw, vt2, Op, Mp, Lp);
  combine_kernel<<<512, 256, 0, stream>>>(Op, Mp, Lp, out);
}